// Round 7
// baseline (140.753 us; speedup 1.0000x reference)
//
#include <hip/hip_runtime.h>
#include <hip/hip_bf16.h>
#include <math.h>

// DirectVoxGO fused forward, v7.
// prep: grid pack (AoS bf16 [voxel][16ch]) + weight MFMA-fragments + per-ray
//       emb table (64 B/ray, fragment-aligned; lk=1's ks1 slot is zeros).
// G: 1 thread/point, no LDS/barriers: packed gathers -> alpha + feat[pt][16].
// M v7: 1 block/ray, 4 waves slice N, launch_bounds(256,4) with a register
//       budget that actually fits 128/wave: GEMM1 in two 64-pt passes (acc 32),
//       GEMM2 c2-outer (acc 32, h2p 32), per-phase weight/bias loads pinned by
//       sched_barrier(0) after each __syncthreads. Coalesced rgb store via
//       wave-private LDS slab.

typedef __bf16 bf16x4 __attribute__((ext_vector_type(4)));
typedef __bf16 bf16x8 __attribute__((ext_vector_type(8)));
typedef float  f32x4  __attribute__((ext_vector_type(4)));

#define ACT_SHIFT_F (-13.815509557964774f)

// ws layout (bytes): wf [0,53248) | emb [53248,315392) | pack [315392,+32MB) | feat
#define EMB_B   53248
#define PACK_B  315392
#define FEAT_B  32315392
#define NEED_FULL 49092608ull
#define NEED_PACK 32315392ull

// ---------------- prep ----------------
// weight elems [0,8192): w1 A-frags [ct=8][ks=2][lane][j=8], k>=39 zeroed
// [8192,24576): w2 A-frags [ct=8][ks=4][lane][j=8]
// [24576,26624): w3 A-frags [ks=4][lane][j=8], cols c>=3 zeroed
// emb[ray][32] bf16: e0..10=sin m1..11 (k16..26), e11..22=cos m0..11 (k27..38),
//                    e23..31 = 0  (bytes [48,64) form a zero b128 slot)
__global__ __launch_bounds__(256)
void dvgo_prep(const float* __restrict__ g_gd, const float* __restrict__ g_gc,
               const float* __restrict__ g_w1, const float* __restrict__ g_w2,
               const float* __restrict__ g_w3, const float* __restrict__ g_dir,
               bf16x8* __restrict__ pack, __bf16* __restrict__ wsb,
               __bf16* __restrict__ emb, int wbase)
{
    const int bid = blockIdx.x;
    if (bid < wbase) {
        const int gi = bid * 256 + threadIdx.x;
        if (gi >= 1000000) return;
        bf16x8 v0, v1;
        #pragma unroll
        for (int c = 0; c < 8; ++c) v0[c] = (__bf16)g_gc[c * 1000000 + gi];
        #pragma unroll
        for (int c = 0; c < 4; ++c) v1[c] = (__bf16)g_gc[(8 + c) * 1000000 + gi];
        v1[4] = (__bf16)g_gd[gi];
        v1[5] = (__bf16)0.0f; v1[6] = (__bf16)0.0f; v1[7] = (__bf16)0.0f;
        pack[gi * 2 + 0] = v0;
        pack[gi * 2 + 1] = v1;
        return;
    }
    const int idx = (bid - wbase) * 256 + threadIdx.x;
    if (idx < 8192) {
        const int j = idx & 7, lane = (idx >> 3) & 63, ks = (idx >> 9) & 1, ct = idx >> 10;
        const int n = ct * 16 + (lane & 15);
        const int k = ks * 32 + ((lane >> 4) & 3) * 8 + j;
        wsb[idx] = (__bf16)((k < 39) ? g_w1[k * 128 + n] : 0.0f);
    } else if (idx < 24576) {
        const int i2 = idx - 8192;
        const int j = i2 & 7, lane = (i2 >> 3) & 63, ks = (i2 >> 9) & 3, ct = i2 >> 11;
        const int n = ct * 16 + (lane & 15);
        const int k = ks * 32 + ((lane >> 4) & 3) * 8 + j;
        wsb[idx] = (__bf16)g_w2[k * 128 + n];
    } else if (idx < 26624) {
        const int i3 = idx - 24576;
        const int j = i3 & 7, lane = (i3 >> 3) & 63, ks = i3 >> 9;
        const int c = lane & 15;
        const int k = ks * 32 + ((lane >> 4) & 3) * 8 + j;
        wsb[idx] = (__bf16)((c < 3) ? g_w3[k * 3 + c] : 0.0f);
    } else if (idx < 30720) {
        const int ray = idx - 26624;
        const float d0 = g_dir[ray*3+0], d1 = g_dir[ray*3+1], d2 = g_dir[ray*3+2];
        __bf16 e[32];
        #pragma unroll
        for (int s = 0; s < 32; ++s) e[s] = (__bf16)0.0f;
        #pragma unroll
        for (int m = 0; m < 12; ++m) {
            const int i = m >> 2, j = m & 3;
            const float di = (i == 0) ? d0 : ((i == 1) ? d1 : d2);
            const float a = di * (float)(1 << j);
            if (m >= 1) e[m - 1] = (__bf16)sinf(a);   // k=16..26
            e[11 + m] = (__bf16)cosf(a);              // k=27..38
        }
        bf16x8* o = (bf16x8*)(emb + (size_t)ray * 32);
        #pragma unroll
        for (int q = 0; q < 4; ++q) {
            bf16x8 v;
            #pragma unroll
            for (int j = 0; j < 8; ++j) v[j] = e[q*8 + j];
            o[q] = v;
        }
    }
}

// ---------------- G: gather, 1 thread/point ----------------
__global__ __launch_bounds__(256, 6)
void dvgo_gather(const float* __restrict__ g_org, const float* __restrict__ g_dir,
                 const float* __restrict__ g_len, const bf16x8* __restrict__ pack,
                 __bf16* __restrict__ feat, float* __restrict__ out_alpha)
{
    const int pt  = blockIdx.x * 256 + threadIdx.x;
    const int ray = pt >> 7;
    const float d0 = g_dir[ray*3+0], d1 = g_dir[ray*3+1], d2 = g_dir[ray*3+2];
    const float o0 = g_org[ray*3+0], o1 = g_org[ray*3+1], o2 = g_org[ray*3+2];
    const float len = g_len[pt];

    const float px = (o0 + d0*len + 1.0f) * 49.5f;
    const float py = (o1 + d1*len + 1.0f) * 49.5f;
    const float pz = (o2 + d2*len + 1.0f) * 49.5f;
    const float fx = floorf(px), fy = floorf(py), fz = floorf(pz);
    const int ix = (int)fx, iy = (int)fy, iz = (int)fz;
    const float qx = px - fx, qy = py - fy, qz = pz - fz;
    const float wxa[2] = {1.0f - qx, qx};
    const float wya[2] = {1.0f - qy, qy};
    const float wza[2] = {1.0f - qz, qz};
    const int  cxa[2] = {min(max(ix,0),99),   min(max(ix+1,0),99)};
    const int  cya[2] = {min(max(iy,0),99),   min(max(iy+1,0),99)};
    const int  cza[2] = {min(max(iz,0),99),   min(max(iz+1,0),99)};
    const bool vxa[2] = {(unsigned)ix < 100u, (unsigned)(ix+1) < 100u};
    const bool vya[2] = {(unsigned)iy < 100u, (unsigned)(iy+1) < 100u};
    const bool vza[2] = {(unsigned)iz < 100u, (unsigned)(iz+1) < 100u};

    float den = 0.0f;
    float cc[12];
    #pragma unroll
    for (int c = 0; c < 12; ++c) cc[c] = 0.0f;

    #pragma unroll
    for (int dz = 0; dz < 2; ++dz)
    #pragma unroll
    for (int dy = 0; dy < 2; ++dy)
    #pragma unroll
    for (int dx = 0; dx < 2; ++dx) {
        float w = wxa[dx] * wya[dy] * wza[dz];
        if (!(vxa[dx] && vya[dy] && vza[dz])) w = 0.0f;
        const int gi = (cza[dz]*100 + cya[dy])*100 + cxa[dx];
        const bf16x8 v0 = pack[gi*2 + 0];
        const bf16x8 v1 = pack[gi*2 + 1];
        #pragma unroll
        for (int c = 0; c < 8; ++c) cc[c]     += w * (float)v0[c];
        #pragma unroll
        for (int c = 0; c < 4; ++c) cc[8 + c] += w * (float)v1[c];
        den += w * (float)v1[4];
    }

    const float interval = sqrtf(d0*d0 + d1*d1 + d2*d2);
    const float e = expf(den + ACT_SHIFT_F);
    out_alpha[pt] = -expm1f(-interval * log1pf(e));

    bf16x8 f0, f1;
    #pragma unroll
    for (int c = 0; c < 8; ++c) f0[c] = (__bf16)cc[c];
    #pragma unroll
    for (int c = 0; c < 4; ++c) f1[c] = (__bf16)cc[8 + c];
    f1[4] = (__bf16)d0; f1[5] = (__bf16)d1; f1[6] = (__bf16)d2;
    f1[7] = (__bf16)sinf(d0);                  // k=15 = sin(d0 * 1.0)
    bf16x8* fo = (bf16x8*)(feat + (size_t)pt * 16);
    fo[0] = f0;
    fo[1] = f1;
}

// ---------------- M: MLP v7 ----------------
__global__ __launch_bounds__(256, 4)
void dvgo_mlp(const bf16x8* __restrict__ wf, const __bf16* __restrict__ emb,
              const __bf16* __restrict__ feat,
              const float* __restrict__ g_b1, const float* __restrict__ g_b2,
              const float* __restrict__ g_b3, float* __restrict__ out_rgb)
{
    __shared__ __align__(16) char smem[32768];   // h[pt=128][n=128] bf16, swizzled
    const int tid  = threadIdx.x;
    const int ray  = blockIdx.x;
    const int lane = tid & 63;
    const int wid  = tid >> 6;
    const int lr   = lane & 15;
    const int lk   = lane >> 4;
    const int sz   = (lr & 7) << 4;

    // precomputed LDS addresses (XOR confined to col field; row stride 256 B)
    int rbase[4];
    #pragma unroll
    for (int ks = 0; ks < 4; ++ks)
        rbase[ks] = lr*256 + ((ks*64 + lk*16) ^ sz);
    int wbase[2];
    #pragma unroll
    for (int c2 = 0; c2 < 2; ++c2)
        wbase[c2] = lr*256 + ((((wid*2 + c2)*32) + lk*8) ^ sz);

    // emb: one b128/lane; slot (lk+2)&3; lk=1's ks1 slot is zeros by construction
    const bf16x8 ev = *(const bf16x8*)(emb + (size_t)ray*32 + (((lk + 2) & 3) * 8));
    bf16x8 zed;
    #pragma unroll
    for (int j = 0; j < 8; ++j) zed[j] = (__bf16)0.0f;
    const bf16x8 bq1 = (lk < 2) ? ev : zed;   // ks1 B-frag (k=32..63)

    // ---- GEMM1 weights (only GEMM1's; nothing else hoisted) ----
    bf16x8 aw1[2][2];
    #pragma unroll
    for (int c2 = 0; c2 < 2; ++c2)
        #pragma unroll
        for (int ks = 0; ks < 2; ++ks)
            aw1[c2][ks] = wf[((wid*2 + c2)*2 + ks)*64 + lane];

    // ---- GEMM1 in two 64-pt passes (acc1 32 regs, ft 16 regs) ----
    #pragma unroll
    for (int h = 0; h < 2; ++h) {
        bf16x8 ft[4];
        #pragma unroll
        for (int r4 = 0; r4 < 4; ++r4) {
            const int pt = ray*128 + (h*4 + r4)*16 + lr;
            ft[r4] = *(const bf16x8*)(feat + (size_t)pt*16 + (lk & 1)*8);
        }
        f32x4 acc1[4][2];
        #pragma unroll
        for (int r4 = 0; r4 < 4; ++r4)
            #pragma unroll
            for (int c2 = 0; c2 < 2; ++c2) acc1[r4][c2] = (f32x4){0.f,0.f,0.f,0.f};
        #pragma unroll
        for (int r4 = 0; r4 < 4; ++r4) {
            const bf16x8 b0 = (lk < 2) ? ft[r4] : ev;
            #pragma unroll
            for (int c2 = 0; c2 < 2; ++c2) {
                acc1[r4][c2] = __builtin_amdgcn_mfma_f32_16x16x32_bf16(aw1[c2][0], b0,  acc1[r4][c2], 0, 0, 0);
                acc1[r4][c2] = __builtin_amdgcn_mfma_f32_16x16x32_bf16(aw1[c2][1], bq1, acc1[r4][c2], 0, 0, 0);
            }
        }
        #pragma unroll
        for (int c2 = 0; c2 < 2; ++c2) {
            const f32x4 b1v = *(const f32x4*)(g_b1 + (wid*2 + c2)*16 + lk*4);
            #pragma unroll
            for (int r4 = 0; r4 < 4; ++r4) {
                bf16x4 hv;
                #pragma unroll
                for (int r = 0; r < 4; ++r)
                    hv[r] = (__bf16)fmaxf(acc1[r4][c2][r] + b1v[r], 0.0f);
                *(bf16x4*)(smem + wbase[c2] + (h*4 + r4)*4096) = hv;
            }
        }
    }
    __syncthreads();   // B1: h1 complete
    __builtin_amdgcn_sched_barrier(0);

    // ---- GEMM2: c2-outer (acc2 32 regs); h2 held in regs (32) until B2 ----
    bf16x4 h2p[2][8];
    #pragma unroll
    for (int c2 = 0; c2 < 2; ++c2) {
        bf16x8 aw2[4];
        #pragma unroll
        for (int ks = 0; ks < 4; ++ks)
            aw2[ks] = wf[1024 + ((wid*2 + c2)*4 + ks)*64 + lane];
        const f32x4 b2v = *(const f32x4*)(g_b2 + (wid*2 + c2)*16 + lk*4);
        f32x4 acc2[8];
        #pragma unroll
        for (int rt = 0; rt < 8; ++rt) acc2[rt] = (f32x4){0.f,0.f,0.f,0.f};
        #pragma unroll
        for (int rt = 0; rt < 8; ++rt) {
            bf16x8 hq[4];
            #pragma unroll
            for (int ks = 0; ks < 4; ++ks)
                hq[ks] = *(const bf16x8*)(smem + rbase[ks] + rt*4096);
            #pragma unroll
            for (int ks = 0; ks < 4; ++ks)
                acc2[rt] = __builtin_amdgcn_mfma_f32_16x16x32_bf16(aw2[ks], hq[ks], acc2[rt], 0, 0, 0);
        }
        #pragma unroll
        for (int rt = 0; rt < 8; ++rt) {
            bf16x4 hv;
            #pragma unroll
            for (int r = 0; r < 4; ++r)
                hv[r] = (__bf16)fmaxf(acc2[rt][r] + b2v[r], 0.0f);
            h2p[c2][rt] = hv;
        }
    }
    __syncthreads();   // B2: all h1 reads done; safe to overwrite with h2
    __builtin_amdgcn_sched_barrier(0);

    #pragma unroll
    for (int c2 = 0; c2 < 2; ++c2)
        #pragma unroll
        for (int rt = 0; rt < 8; ++rt)
            *(bf16x4*)(smem + wbase[c2] + rt*4096) = h2p[c2][rt];
    __syncthreads();   // B3: h2 complete
    __builtin_amdgcn_sched_barrier(0);

    // ---- GEMM3: wave's own 2 pt-tiles (rows in own slab), w3 padded ----
    bf16x8 aw3[4];
    #pragma unroll
    for (int ks = 0; ks < 4; ++ks) aw3[ks] = wf[3072 + ks*64 + lane];
    const int g3 = wid * 8192;
    f32x4 acc3[2];
    acc3[0] = (f32x4){0.f,0.f,0.f,0.f};
    acc3[1] = (f32x4){0.f,0.f,0.f,0.f};
    #pragma unroll
    for (int q = 0; q < 2; ++q)
        #pragma unroll
        for (int ks = 0; ks < 4; ++ks) {
            const bf16x8 hq = *(const bf16x8*)(smem + rbase[ks] + g3 + q*4096);
            acc3[q] = __builtin_amdgcn_mfma_f32_16x16x32_bf16(aw3[ks], hq, acc3[q], 0, 0, 0);
        }

    // ---- sigmoid -> wave-private LDS staging -> coalesced store ----
    float* smf = (float*)(smem + wid*8192);   // own slab (all its reads done)
    if (lk == 0) {
        const float b30 = g_b3[0], b31 = g_b3[1], b32 = g_b3[2];
        #pragma unroll
        for (int q = 0; q < 2; ++q) {
            const int o = (q*16 + lr)*3;
            smf[o + 0] = 1.0f / (1.0f + __expf(-(acc3[q][0] + b30)));
            smf[o + 1] = 1.0f / (1.0f + __expf(-(acc3[q][1] + b31)));
            smf[o + 2] = 1.0f / (1.0f + __expf(-(acc3[q][2] + b32)));
        }
    }
    asm volatile("s_waitcnt lgkmcnt(0)");     // wave-internal LDS drain
    __builtin_amdgcn_sched_barrier(0);        // rule #18: pin reads after wait
    {
        const int base = (ray*128 + wid*32)*3;    // 96 contiguous floats
        out_rgb[base + lane] = smf[lane];
        if (lane < 32) out_rgb[base + 64 + lane] = smf[64 + lane];
    }
}

// ================= fallback fused kernel (v3, proven) =================
#define FB_FEAT_OFF 0
#define FB_PCC_OFF  16384
#define FB_H1_OFF   0
#define FB_PRGB_OFF 0

template <bool PACKED>
__global__ __launch_bounds__(256, 4)
void dvgo_main(const float* __restrict__ g_org, const float* __restrict__ g_dir,
               const float* __restrict__ g_len, const float* __restrict__ g_gd,
               const float* __restrict__ g_gc, const float* __restrict__ g_b1,
               const float* __restrict__ g_b2, const float* __restrict__ g_w3,
               const float* __restrict__ g_b3, const bf16x8* __restrict__ wf,
               const bf16x8* __restrict__ g_pack,
               float* __restrict__ out_alpha, float* __restrict__ out_rgb)
{
    __shared__ __align__(16) char smem[32768];
    float* smf = (float*)smem;
    const int tid = threadIdx.x;
    const int ray = blockIdx.x;
    const float d0 = g_dir[ray*3+0], d1 = g_dir[ray*3+1], d2 = g_dir[ray*3+2];
    {
        const float o0 = g_org[ray*3+0], o1 = g_org[ray*3+1], o2 = g_org[ray*3+2];
        const int p = tid & 127;
        const int dzv = tid >> 7;
        const float len = g_len[ray*128 + p];
        const float px = (o0 + d0*len + 1.0f) * 49.5f;
        const float py = (o1 + d1*len + 1.0f) * 49.5f;
        const float pz = (o2 + d2*len + 1.0f) * 49.5f;
        const float fx = floorf(px), fy = floorf(py), fz = floorf(pz);
        const int ix = (int)fx, iy = (int)fy, iz0 = (int)fz;
        const float qx = px - fx, qy = py - fy, qz = pz - fz;
        const float wxa[2] = {1.0f - qx, qx};
        const float wya[2] = {1.0f - qy, qy};
        const int  cxa[2] = {min(max(ix,0),99),   min(max(ix+1,0),99)};
        const int  cya[2] = {min(max(iy,0),99),   min(max(iy+1,0),99)};
        const bool vxa[2] = {(unsigned)ix < 100u, (unsigned)(ix+1) < 100u};
        const bool vya[2] = {(unsigned)iy < 100u, (unsigned)(iy+1) < 100u};
        const int  iz = iz0 + dzv;
        const float wz = dzv ? qz : (1.0f - qz);
        const int  cz = min(max(iz,0),99);
        const bool vz = (unsigned)iz < 100u;
        float den = 0.0f;
        float cc[12];
        #pragma unroll
        for (int c = 0; c < 12; ++c) cc[c] = 0.0f;
        #pragma unroll
        for (int dy = 0; dy < 2; ++dy)
        #pragma unroll
        for (int dx = 0; dx < 2; ++dx) {
            float w = wxa[dx] * wya[dy] * wz;
            if (!(vxa[dx] && vya[dy] && vz)) w = 0.0f;
            const int gi = (cz*100 + cya[dy])*100 + cxa[dx];
            if (PACKED) {
                const bf16x8 v0 = g_pack[gi*2 + 0];
                const bf16x8 v1 = g_pack[gi*2 + 1];
                #pragma unroll
                for (int c = 0; c < 8; ++c) cc[c]     += w * (float)v0[c];
                #pragma unroll
                for (int c = 0; c < 4; ++c) cc[8 + c] += w * (float)v1[c];
                den += w * (float)v1[4];
            } else {
                den += w * g_gd[gi];
                #pragma unroll
                for (int c = 0; c < 12; ++c) cc[c] += w * g_gc[c*1000000 + gi];
            }
        }
        if (dzv) {
            #pragma unroll
            for (int c = 0; c < 12; ++c) smf[FB_PCC_OFF/4 + p*13 + c] = cc[c];
            smf[FB_PCC_OFF/4 + p*13 + 12] = den;
        }
        __syncthreads();
        if (!dzv) {
            #pragma unroll
            for (int c = 0; c < 12; ++c) cc[c] += smf[FB_PCC_OFF/4 + p*13 + c];
            den += smf[FB_PCC_OFF/4 + p*13 + 12];
            const float interval = sqrtf(d0*d0 + d1*d1 + d2*d2);
            const float e = expf(den + ACT_SHIFT_F);
            out_alpha[ray*128 + p] = -expm1f(-interval * log1pf(e));
            bf16x8 f0; bf16x4 f1;
            #pragma unroll
            for (int c = 0; c < 8; ++c) f0[c] = (__bf16)cc[c];
            #pragma unroll
            for (int c = 0; c < 4; ++c) f1[c] = (__bf16)cc[8+c];
            const int swz = (p & 7) << 4;
            *reinterpret_cast<bf16x8*>(smem + ((FB_FEAT_OFF + p*128 +  0) ^ swz)) = f0;
            *reinterpret_cast<bf16x4*>(smem + ((FB_FEAT_OFF + p*128 + 16) ^ swz)) = f1;
        } else {
            float vals[52];
            vals[0] = d0; vals[1] = d1; vals[2] = d2;
            #pragma unroll
            for (int i = 0; i < 3; ++i) {
                const float di = (i == 0) ? d0 : ((i == 1) ? d1 : d2);
                #pragma unroll
                for (int j = 0; j < 4; ++j) {
                    const float a = di * (float)(1 << j);
                    vals[3  + i*4 + j] = sinf(a);
                    vals[15 + i*4 + j] = cosf(a);
                }
            }
            #pragma unroll
            for (int c = 27; c < 52; ++c) vals[c] = 0.0f;
            const int swz = (p & 7) << 4;
            #pragma unroll
            for (int i = 0; i < 13; ++i) {
                bf16x4 v4;
                #pragma unroll
                for (int r = 0; r < 4; ++r) v4[r] = (__bf16)vals[i*4 + r];
                *reinterpret_cast<bf16x4*>(smem + ((FB_FEAT_OFF + p*128 + 24 + i*8) ^ swz)) = v4;
            }
        }
    }
    __syncthreads();
    const int lane = tid & 63;
    const int wid  = tid >> 6;
    const int lr   = lane & 15;
    const int lk   = lane >> 4;
    {
        bf16x8 bf[2][2];
        #pragma unroll
        for (int rt = 0; rt < 2; ++rt)
            #pragma unroll
            for (int ks = 0; ks < 2; ++ks) {
                const int pt = wid*32 + rt*16 + lr;
                int a = FB_FEAT_OFF + pt*128 + ks*64 + lk*16; a ^= (pt & 7) << 4;
                bf[rt][ks] = *reinterpret_cast<const bf16x8*>(smem + a);
            }
        __syncthreads();
        f32x4 acc1[2][8];
        #pragma unroll
        for (int rt = 0; rt < 2; ++rt)
            #pragma unroll
            for (int ct = 0; ct < 8; ++ct) acc1[rt][ct] = (f32x4){0.f,0.f,0.f,0.f};
        #pragma unroll
        for (int ct = 0; ct < 8; ++ct) {
            const bf16x8 aw0 = wf[(ct*2 + 0)*64 + lane];
            const bf16x8 aw1 = wf[(ct*2 + 1)*64 + lane];
            #pragma unroll
            for (int rt = 0; rt < 2; ++rt) {
                acc1[rt][ct] = __builtin_amdgcn_mfma_f32_16x16x32_bf16(aw0, bf[rt][0], acc1[rt][ct], 0, 0, 0);
                acc1[rt][ct] = __builtin_amdgcn_mfma_f32_16x16x32_bf16(aw1, bf[rt][1], acc1[rt][ct], 0, 0, 0);
            }
        }
        #pragma unroll
        for (int ct = 0; ct < 8; ++ct) {
            const f32x4 b1v = *reinterpret_cast<const f32x4*>(g_b1 + ct*16 + lk*4);
            #pragma unroll
            for (int rt = 0; rt < 2; ++rt) {
                const int pt = wid*32 + rt*16 + lr;
                bf16x4 hv;
                #pragma unroll
                for (int r = 0; r < 4; ++r)
                    hv[r] = (__bf16)fmaxf(acc1[rt][ct][r] + b1v[r], 0.0f);
                int a = FB_H1_OFF + pt*256 + ct*32 + lk*8; a ^= (pt & 7) << 4;
                *reinterpret_cast<bf16x4*>(smem + a) = hv;
            }
        }
    }
    __syncthreads();
    const int wr = wid >> 1, wc = wid & 1;
    f32x4 acc2[4][4];
    #pragma unroll
    for (int rt = 0; rt < 4; ++rt)
        #pragma unroll
        for (int ct = 0; ct < 4; ++ct) acc2[rt][ct] = (f32x4){0.f,0.f,0.f,0.f};
    #pragma unroll
    for (int ks = 0; ks < 4; ++ks) {
        bf16x8 a2[4];
        #pragma unroll
        for (int rt = 0; rt < 4; ++rt) {
            const int pt = wr*64 + rt*16 + lr;
            int a = FB_H1_OFF + pt*256 + ks*64 + lk*16; a ^= (pt & 7) << 4;
            a2[rt] = *reinterpret_cast<const bf16x8*>(smem + a);
        }
        #pragma unroll
        for (int ct = 0; ct < 4; ++ct) {
            const int ctg = wc*4 + ct;
            const bf16x8 b2f = wf[1024 + (ctg*4 + ks)*64 + lane];
            #pragma unroll
            for (int rt = 0; rt < 4; ++rt)
                acc2[rt][ct] = __builtin_amdgcn_mfma_f32_16x16x32_bf16(a2[rt], b2f, acc2[rt][ct], 0, 0, 0);
        }
    }
    __syncthreads();
    {
        float b2v[4], w30[4], w31[4], w32[4];
        #pragma unroll
        for (int ct = 0; ct < 4; ++ct) {
            const int n2 = wc*64 + ct*16 + lr;
            b2v[ct] = g_b2[n2];
            w30[ct] = g_w3[n2*3 + 0];
            w31[ct] = g_w3[n2*3 + 1];
            w32[ct] = g_w3[n2*3 + 2];
        }
        #pragma unroll
        for (int rt = 0; rt < 4; ++rt)
            #pragma unroll
            for (int r = 0; r < 4; ++r) {
                float s0 = 0.f, s1 = 0.f, s2 = 0.f;
                #pragma unroll
                for (int ct = 0; ct < 4; ++ct) {
                    const float v = fmaxf(acc2[rt][ct][r] + b2v[ct], 0.0f);
                    s0 = fmaf(v, w30[ct], s0);
                    s1 = fmaf(v, w31[ct], s1);
                    s2 = fmaf(v, w32[ct], s2);
                }
                #pragma unroll
                for (int off = 1; off < 16; off <<= 1) {
                    s0 += __shfl_xor(s0, off);
                    s1 += __shfl_xor(s1, off);
                    s2 += __shfl_xor(s2, off);
                }
                if (lr == 0) {
                    const int pt = wr*64 + rt*16 + lk*4 + r;
                    const int base = FB_PRGB_OFF/4 + (wc*128 + pt)*3;
                    smf[base + 0] = s0;
                    smf[base + 1] = s1;
                    smf[base + 2] = s2;
                }
            }
    }
    __syncthreads();
    if (tid < 128) {
        const int p = tid;
        const float s0 = smf[p*3 + 0] + smf[(128 + p)*3 + 0] + g_b3[0];
        const float s1 = smf[p*3 + 1] + smf[(128 + p)*3 + 1] + g_b3[1];
        const float s2 = smf[p*3 + 2] + smf[(128 + p)*3 + 2] + g_b3[2];
        const int pt = ray*128 + p;
        out_rgb[pt*3 + 0] = 1.0f / (1.0f + expf(-s0));
        out_rgb[pt*3 + 1] = 1.0f / (1.0f + expf(-s1));
        out_rgb[pt*3 + 2] = 1.0f / (1.0f + expf(-s2));
    }
}

extern "C" void kernel_launch(void* const* d_in, const int* in_sizes, int n_in,
                              void* d_out, int out_size, void* d_ws, size_t ws_size,
                              hipStream_t stream)
{
    const float* g_org = (const float*)d_in[0];
    const float* g_dir = (const float*)d_in[1];
    const float* g_len = (const float*)d_in[2];
    const float* g_gd  = (const float*)d_in[3];
    const float* g_gc  = (const float*)d_in[4];
    const float* g_w1  = (const float*)d_in[5];
    const float* g_b1  = (const float*)d_in[6];
    const float* g_w2  = (const float*)d_in[7];
    const float* g_b2  = (const float*)d_in[8];
    const float* g_w3  = (const float*)d_in[9];
    const float* g_b3  = (const float*)d_in[10];
    float* out = (float*)d_out;

    __bf16* wsb  = (__bf16*)d_ws;
    __bf16* emb  = (__bf16*)((char*)d_ws + EMB_B);
    bf16x8* pack = (bf16x8*)((char*)d_ws + PACK_B);

    if (ws_size >= NEED_FULL) {
        __bf16* feat = (__bf16*)((char*)d_ws + FEAT_B);
        dvgo_prep<<<4027, 256, 0, stream>>>(g_gd, g_gc, g_w1, g_w2, g_w3, g_dir,
                                            pack, wsb, emb, 3907);
        dvgo_gather<<<2048, 256, 0, stream>>>(g_org, g_dir, g_len, pack, feat, out);
        dvgo_mlp<<<4096, 256, 0, stream>>>((const bf16x8*)wsb, emb, feat,
                                           g_b1, g_b2, g_b3, out + 4096*128);
    } else if (ws_size >= NEED_PACK) {
        dvgo_prep<<<4011, 256, 0, stream>>>(g_gd, g_gc, g_w1, g_w2, g_w3, g_dir,
                                            pack, wsb, emb, 3907);
        dvgo_main<true><<<4096, 256, 0, stream>>>(g_org, g_dir, g_len, g_gd, g_gc,
                                                  g_b1, g_b2, g_w3, g_b3,
                                                  (const bf16x8*)wsb, pack,
                                                  out, out + 4096*128);
    } else {
        dvgo_prep<<<104, 256, 0, stream>>>(g_gd, g_gc, g_w1, g_w2, g_w3, g_dir,
                                           pack, wsb, emb, 0);
        dvgo_main<false><<<4096, 256, 0, stream>>>(g_org, g_dir, g_len, g_gd, g_gc,
                                                   g_b1, g_b2, g_w3, g_b3,
                                                   (const bf16x8*)wsb, nullptr,
                                                   out, out + 4096*128);
    }
}

// Round 8
// 77.285 us; speedup vs baseline: 1.8212x; 1.8212x over previous
//
#include <hip/hip_runtime.h>
#include <hip/hip_bf16.h>
#include <math.h>

// DirectVoxGO fused forward, v8.
// prep: grid pack (AoS bf16 [voxel][16ch]) + weight MFMA-fragments + per-ray
//       emb table (64 B/ray, fragment-aligned; lk=1's ks1 slot is zeros).
// G: 1 thread/point, no LDS/barriers: packed gathers -> alpha + feat[pt][16].
// M v8: ONE barrier. GEMM1 slice-N (weights 4 frags/wave, acc 32, 2 passes)
//       -> h1 tile -> B1 -> GEMM2 pt-slice (own 32 pts x all n2; per-ct acc=8,
//       immediate relu/cvt/LDS-write; h1 rows pre-read into hq regs) -> GEMM3
//       private -> coalesced rgb. Peak ~100 regs @ launch_bounds(256,3).

typedef __bf16 bf16x4 __attribute__((ext_vector_type(4)));
typedef __bf16 bf16x8 __attribute__((ext_vector_type(8)));
typedef float  f32x4  __attribute__((ext_vector_type(4)));

#define ACT_SHIFT_F (-13.815509557964774f)

// ws layout (bytes): wf [0,53248) | emb [53248,315392) | pack [315392,+32MB) | feat
#define EMB_B   53248
#define PACK_B  315392
#define FEAT_B  32315392
#define NEED_FULL 49092608ull
#define NEED_PACK 32315392ull

// ---------------- prep ----------------
// weight elems [0,8192): w1 A-frags [ct=8][ks=2][lane][j=8], k>=39 zeroed
// [8192,24576): w2 A-frags [ct=8][ks=4][lane][j=8]
// [24576,26624): w3 A-frags [ks=4][lane][j=8], cols c>=3 zeroed
// emb[ray][32] bf16: e0..10=sin m1..11 (k16..26), e11..22=cos m0..11 (k27..38),
//                    e23..31 = 0  (bytes [48,64) form a zero b128 slot)
__global__ __launch_bounds__(256)
void dvgo_prep(const float* __restrict__ g_gd, const float* __restrict__ g_gc,
               const float* __restrict__ g_w1, const float* __restrict__ g_w2,
               const float* __restrict__ g_w3, const float* __restrict__ g_dir,
               bf16x8* __restrict__ pack, __bf16* __restrict__ wsb,
               __bf16* __restrict__ emb, int wbase)
{
    const int bid = blockIdx.x;
    if (bid < wbase) {
        const int gi = bid * 256 + threadIdx.x;
        if (gi >= 1000000) return;
        bf16x8 v0, v1;
        #pragma unroll
        for (int c = 0; c < 8; ++c) v0[c] = (__bf16)g_gc[c * 1000000 + gi];
        #pragma unroll
        for (int c = 0; c < 4; ++c) v1[c] = (__bf16)g_gc[(8 + c) * 1000000 + gi];
        v1[4] = (__bf16)g_gd[gi];
        v1[5] = (__bf16)0.0f; v1[6] = (__bf16)0.0f; v1[7] = (__bf16)0.0f;
        pack[gi * 2 + 0] = v0;
        pack[gi * 2 + 1] = v1;
        return;
    }
    const int idx = (bid - wbase) * 256 + threadIdx.x;
    if (idx < 8192) {
        const int j = idx & 7, lane = (idx >> 3) & 63, ks = (idx >> 9) & 1, ct = idx >> 10;
        const int n = ct * 16 + (lane & 15);
        const int k = ks * 32 + ((lane >> 4) & 3) * 8 + j;
        wsb[idx] = (__bf16)((k < 39) ? g_w1[k * 128 + n] : 0.0f);
    } else if (idx < 24576) {
        const int i2 = idx - 8192;
        const int j = i2 & 7, lane = (i2 >> 3) & 63, ks = (i2 >> 9) & 3, ct = i2 >> 11;
        const int n = ct * 16 + (lane & 15);
        const int k = ks * 32 + ((lane >> 4) & 3) * 8 + j;
        wsb[idx] = (__bf16)g_w2[k * 128 + n];
    } else if (idx < 26624) {
        const int i3 = idx - 24576;
        const int j = i3 & 7, lane = (i3 >> 3) & 63, ks = i3 >> 9;
        const int c = lane & 15;
        const int k = ks * 32 + ((lane >> 4) & 3) * 8 + j;
        wsb[idx] = (__bf16)((c < 3) ? g_w3[k * 3 + c] : 0.0f);
    } else if (idx < 30720) {
        const int ray = idx - 26624;
        const float d0 = g_dir[ray*3+0], d1 = g_dir[ray*3+1], d2 = g_dir[ray*3+2];
        __bf16 e[32];
        #pragma unroll
        for (int s = 0; s < 32; ++s) e[s] = (__bf16)0.0f;
        #pragma unroll
        for (int m = 0; m < 12; ++m) {
            const int i = m >> 2, j = m & 3;
            const float di = (i == 0) ? d0 : ((i == 1) ? d1 : d2);
            const float a = di * (float)(1 << j);
            if (m >= 1) e[m - 1] = (__bf16)sinf(a);   // k=16..26
            e[11 + m] = (__bf16)cosf(a);              // k=27..38
        }
        bf16x8* o = (bf16x8*)(emb + (size_t)ray * 32);
        #pragma unroll
        for (int q = 0; q < 4; ++q) {
            bf16x8 v;
            #pragma unroll
            for (int j = 0; j < 8; ++j) v[j] = e[q*8 + j];
            o[q] = v;
        }
    }
}

// ---------------- G: gather, 1 thread/point ----------------
__global__ __launch_bounds__(256, 6)
void dvgo_gather(const float* __restrict__ g_org, const float* __restrict__ g_dir,
                 const float* __restrict__ g_len, const bf16x8* __restrict__ pack,
                 __bf16* __restrict__ feat, float* __restrict__ out_alpha)
{
    const int pt  = blockIdx.x * 256 + threadIdx.x;
    const int ray = pt >> 7;
    const float d0 = g_dir[ray*3+0], d1 = g_dir[ray*3+1], d2 = g_dir[ray*3+2];
    const float o0 = g_org[ray*3+0], o1 = g_org[ray*3+1], o2 = g_org[ray*3+2];
    const float len = g_len[pt];

    const float px = (o0 + d0*len + 1.0f) * 49.5f;
    const float py = (o1 + d1*len + 1.0f) * 49.5f;
    const float pz = (o2 + d2*len + 1.0f) * 49.5f;
    const float fx = floorf(px), fy = floorf(py), fz = floorf(pz);
    const int ix = (int)fx, iy = (int)fy, iz = (int)fz;
    const float qx = px - fx, qy = py - fy, qz = pz - fz;
    const float wxa[2] = {1.0f - qx, qx};
    const float wya[2] = {1.0f - qy, qy};
    const float wza[2] = {1.0f - qz, qz};
    const int  cxa[2] = {min(max(ix,0),99),   min(max(ix+1,0),99)};
    const int  cya[2] = {min(max(iy,0),99),   min(max(iy+1,0),99)};
    const int  cza[2] = {min(max(iz,0),99),   min(max(iz+1,0),99)};
    const bool vxa[2] = {(unsigned)ix < 100u, (unsigned)(ix+1) < 100u};
    const bool vya[2] = {(unsigned)iy < 100u, (unsigned)(iy+1) < 100u};
    const bool vza[2] = {(unsigned)iz < 100u, (unsigned)(iz+1) < 100u};

    float den = 0.0f;
    float cc[12];
    #pragma unroll
    for (int c = 0; c < 12; ++c) cc[c] = 0.0f;

    #pragma unroll
    for (int dz = 0; dz < 2; ++dz)
    #pragma unroll
    for (int dy = 0; dy < 2; ++dy)
    #pragma unroll
    for (int dx = 0; dx < 2; ++dx) {
        float w = wxa[dx] * wya[dy] * wza[dz];
        if (!(vxa[dx] && vya[dy] && vza[dz])) w = 0.0f;
        const int gi = (cza[dz]*100 + cya[dy])*100 + cxa[dx];
        const bf16x8 v0 = pack[gi*2 + 0];
        const bf16x8 v1 = pack[gi*2 + 1];
        #pragma unroll
        for (int c = 0; c < 8; ++c) cc[c]     += w * (float)v0[c];
        #pragma unroll
        for (int c = 0; c < 4; ++c) cc[8 + c] += w * (float)v1[c];
        den += w * (float)v1[4];
    }

    const float interval = sqrtf(d0*d0 + d1*d1 + d2*d2);
    const float e = expf(den + ACT_SHIFT_F);
    out_alpha[pt] = -expm1f(-interval * log1pf(e));

    bf16x8 f0, f1;
    #pragma unroll
    for (int c = 0; c < 8; ++c) f0[c] = (__bf16)cc[c];
    #pragma unroll
    for (int c = 0; c < 4; ++c) f1[c] = (__bf16)cc[8 + c];
    f1[4] = (__bf16)d0; f1[5] = (__bf16)d1; f1[6] = (__bf16)d2;
    f1[7] = (__bf16)sinf(d0);                  // k=15 = sin(d0 * 1.0)
    bf16x8* fo = (bf16x8*)(feat + (size_t)pt * 16);
    fo[0] = f0;
    fo[1] = f1;
}

// ---------------- M: MLP v8 (one barrier) ----------------
__global__ __launch_bounds__(256, 3)
void dvgo_mlp(const bf16x8* __restrict__ wf, const __bf16* __restrict__ emb,
              const __bf16* __restrict__ feat,
              const float* __restrict__ g_b1, const float* __restrict__ g_b2,
              const float* __restrict__ g_b3, float* __restrict__ out_rgb)
{
    __shared__ __align__(16) char smem[32768];   // h[pt=128][n=128] bf16, swizzled
    const int tid  = threadIdx.x;
    const int ray  = blockIdx.x;
    const int lane = tid & 63;
    const int wid  = tid >> 6;
    const int lr   = lane & 15;
    const int lk   = lane >> 4;
    const int sz   = (lr & 7) << 4;

    // h1 write bases (slice-N: this wave's n-cols, rows rt*16+lr for all rt)
    int wb1[2];
    #pragma unroll
    for (int c2 = 0; c2 < 2; ++c2)
        wb1[c2] = lr*256 + ((((wid*2 + c2)*32) + lk*8) ^ sz);
    // own-slab k-frag read bases (GEMM2 hq + GEMM3): row = wid*32 + q*16 + lr
    int rb2[4];
    #pragma unroll
    for (int ks = 0; ks < 4; ++ks)
        rb2[ks] = (wid*32 + lr)*256 + ((ks*64 + lk*16) ^ sz);
    const int rowb = (wid*32 + lr)*256;          // h2 write row base

    // emb: one b128/lane; slot (lk+2)&3; lk=1's ks1 slot is zeros by construction
    const bf16x8 ev = *(const bf16x8*)(emb + (size_t)ray*32 + (((lk + 2) & 3) * 8));
    bf16x8 zed;
    #pragma unroll
    for (int j = 0; j < 8; ++j) zed[j] = (__bf16)0.0f;
    const bf16x8 bq1 = (lk < 2) ? ev : zed;      // ks1 B-frag (k=32..63)

    // ---- GEMM1 (slice-N), two 64-pt passes; acc 32 regs ----
    bf16x8 aw1[2][2];
    #pragma unroll
    for (int c2 = 0; c2 < 2; ++c2)
        #pragma unroll
        for (int ks = 0; ks < 2; ++ks)
            aw1[c2][ks] = wf[((wid*2 + c2)*2 + ks)*64 + lane];

    #pragma unroll
    for (int h = 0; h < 2; ++h) {
        bf16x8 ft[4];
        #pragma unroll
        for (int r4 = 0; r4 < 4; ++r4) {
            const int pt = ray*128 + (h*4 + r4)*16 + lr;
            ft[r4] = *(const bf16x8*)(feat + (size_t)pt*16 + (lk & 1)*8);
        }
        f32x4 acc1[4][2];
        #pragma unroll
        for (int r4 = 0; r4 < 4; ++r4)
            #pragma unroll
            for (int c2 = 0; c2 < 2; ++c2) acc1[r4][c2] = (f32x4){0.f,0.f,0.f,0.f};
        #pragma unroll
        for (int r4 = 0; r4 < 4; ++r4) {
            const bf16x8 b0 = (lk < 2) ? ft[r4] : ev;
            #pragma unroll
            for (int c2 = 0; c2 < 2; ++c2) {
                acc1[r4][c2] = __builtin_amdgcn_mfma_f32_16x16x32_bf16(aw1[c2][0], b0,  acc1[r4][c2], 0, 0, 0);
                acc1[r4][c2] = __builtin_amdgcn_mfma_f32_16x16x32_bf16(aw1[c2][1], bq1, acc1[r4][c2], 0, 0, 0);
            }
        }
        #pragma unroll
        for (int c2 = 0; c2 < 2; ++c2) {
            const f32x4 b1v = *(const f32x4*)(g_b1 + (wid*2 + c2)*16 + lk*4);
            #pragma unroll
            for (int r4 = 0; r4 < 4; ++r4) {
                bf16x4 hv;
                #pragma unroll
                for (int r = 0; r < 4; ++r)
                    hv[r] = (__bf16)fmaxf(acc1[r4][c2][r] + b1v[r], 0.0f);
                *(bf16x4*)(smem + wb1[c2] + (h*4 + r4)*4096) = hv;
            }
        }
    }
    __syncthreads();   // B1: h1 complete (the ONLY barrier)

    // ---- GEMM2 (pt-slice): own 32 pts x all 128 n2; per-ct acc = 8 regs ----
    bf16x8 hq[2][4];   // own rows' h1, all k
    #pragma unroll
    for (int q = 0; q < 2; ++q)
        #pragma unroll
        for (int ks = 0; ks < 4; ++ks)
            hq[q][ks] = *(const bf16x8*)(smem + rb2[ks] + q*4096);

    #pragma unroll
    for (int ct = 0; ct < 8; ++ct) {
        bf16x8 aw2[4];
        #pragma unroll
        for (int ks = 0; ks < 4; ++ks)
            aw2[ks] = wf[1024 + (ct*4 + ks)*64 + lane];
        f32x4 a0 = (f32x4){0.f,0.f,0.f,0.f};
        f32x4 a1 = (f32x4){0.f,0.f,0.f,0.f};
        #pragma unroll
        for (int ks = 0; ks < 4; ++ks) {
            a0 = __builtin_amdgcn_mfma_f32_16x16x32_bf16(aw2[ks], hq[0][ks], a0, 0, 0, 0);
            a1 = __builtin_amdgcn_mfma_f32_16x16x32_bf16(aw2[ks], hq[1][ks], a1, 0, 0, 0);
        }
        const f32x4 b2v = *(const f32x4*)(g_b2 + ct*16 + lk*4);
        bf16x4 h0, h1;
        #pragma unroll
        for (int r = 0; r < 4; ++r) {
            h0[r] = (__bf16)fmaxf(a0[r] + b2v[r], 0.0f);
            h1[r] = (__bf16)fmaxf(a1[r] + b2v[r], 0.0f);
        }
        const int csw = (ct*32 + lk*8) ^ sz;
        *(bf16x4*)(smem + rowb + csw) = h0;            // h2[own row q=0][n2]
        *(bf16x4*)(smem + rowb + 4096 + csw) = h1;     // h2[own row q=1][n2]
    }

    // ---- GEMM3: own 2 pt-tiles, w3 padded to 16 cols ----
    bf16x8 aw3[4];
    #pragma unroll
    for (int ks = 0; ks < 4; ++ks) aw3[ks] = wf[3072 + ks*64 + lane];
    f32x4 acc3[2];
    acc3[0] = (f32x4){0.f,0.f,0.f,0.f};
    acc3[1] = (f32x4){0.f,0.f,0.f,0.f};
    #pragma unroll
    for (int q = 0; q < 2; ++q)
        #pragma unroll
        for (int ks = 0; ks < 4; ++ks) {
            const bf16x8 hq3 = *(const bf16x8*)(smem + rb2[ks] + q*4096);
            acc3[q] = __builtin_amdgcn_mfma_f32_16x16x32_bf16(aw3[ks], hq3, acc3[q], 0, 0, 0);
        }

    // ---- sigmoid -> wave-private LDS staging -> coalesced store ----
    float* smf = (float*)(smem + wid*8192);   // own slab (all its reads done)
    if (lk == 0) {
        const float b30 = g_b3[0], b31 = g_b3[1], b32 = g_b3[2];
        #pragma unroll
        for (int q = 0; q < 2; ++q) {
            const int o = (q*16 + lr)*3;
            smf[o + 0] = 1.0f / (1.0f + __expf(-(acc3[q][0] + b30)));
            smf[o + 1] = 1.0f / (1.0f + __expf(-(acc3[q][1] + b31)));
            smf[o + 2] = 1.0f / (1.0f + __expf(-(acc3[q][2] + b32)));
        }
    }
    asm volatile("s_waitcnt lgkmcnt(0)");     // wave-internal LDS drain
    __builtin_amdgcn_sched_barrier(0);        // rule #18: pin reads after wait
    {
        const int base = (ray*128 + wid*32)*3;    // 96 contiguous floats
        out_rgb[base + lane] = smf[lane];
        if (lane < 32) out_rgb[base + 64 + lane] = smf[64 + lane];
    }
}

// ================= fallback fused kernel (v3, proven) =================
#define FB_FEAT_OFF 0
#define FB_PCC_OFF  16384
#define FB_H1_OFF   0
#define FB_PRGB_OFF 0

template <bool PACKED>
__global__ __launch_bounds__(256, 4)
void dvgo_main(const float* __restrict__ g_org, const float* __restrict__ g_dir,
               const float* __restrict__ g_len, const float* __restrict__ g_gd,
               const float* __restrict__ g_gc, const float* __restrict__ g_b1,
               const float* __restrict__ g_b2, const float* __restrict__ g_w3,
               const float* __restrict__ g_b3, const bf16x8* __restrict__ wf,
               const bf16x8* __restrict__ g_pack,
               float* __restrict__ out_alpha, float* __restrict__ out_rgb)
{
    __shared__ __align__(16) char smem[32768];
    float* smf = (float*)smem;
    const int tid = threadIdx.x;
    const int ray = blockIdx.x;
    const float d0 = g_dir[ray*3+0], d1 = g_dir[ray*3+1], d2 = g_dir[ray*3+2];
    {
        const float o0 = g_org[ray*3+0], o1 = g_org[ray*3+1], o2 = g_org[ray*3+2];
        const int p = tid & 127;
        const int dzv = tid >> 7;
        const float len = g_len[ray*128 + p];
        const float px = (o0 + d0*len + 1.0f) * 49.5f;
        const float py = (o1 + d1*len + 1.0f) * 49.5f;
        const float pz = (o2 + d2*len + 1.0f) * 49.5f;
        const float fx = floorf(px), fy = floorf(py), fz = floorf(pz);
        const int ix = (int)fx, iy = (int)fy, iz0 = (int)fz;
        const float qx = px - fx, qy = py - fy, qz = pz - fz;
        const float wxa[2] = {1.0f - qx, qx};
        const float wya[2] = {1.0f - qy, qy};
        const int  cxa[2] = {min(max(ix,0),99),   min(max(ix+1,0),99)};
        const int  cya[2] = {min(max(iy,0),99),   min(max(iy+1,0),99)};
        const bool vxa[2] = {(unsigned)ix < 100u, (unsigned)(ix+1) < 100u};
        const bool vya[2] = {(unsigned)iy < 100u, (unsigned)(iy+1) < 100u};
        const int  iz = iz0 + dzv;
        const float wz = dzv ? qz : (1.0f - qz);
        const int  cz = min(max(iz,0),99);
        const bool vz = (unsigned)iz < 100u;
        float den = 0.0f;
        float cc[12];
        #pragma unroll
        for (int c = 0; c < 12; ++c) cc[c] = 0.0f;
        #pragma unroll
        for (int dy = 0; dy < 2; ++dy)
        #pragma unroll
        for (int dx = 0; dx < 2; ++dx) {
            float w = wxa[dx] * wya[dy] * wz;
            if (!(vxa[dx] && vya[dy] && vz)) w = 0.0f;
            const int gi = (cz*100 + cya[dy])*100 + cxa[dx];
            if (PACKED) {
                const bf16x8 v0 = g_pack[gi*2 + 0];
                const bf16x8 v1 = g_pack[gi*2 + 1];
                #pragma unroll
                for (int c = 0; c < 8; ++c) cc[c]     += w * (float)v0[c];
                #pragma unroll
                for (int c = 0; c < 4; ++c) cc[8 + c] += w * (float)v1[c];
                den += w * (float)v1[4];
            } else {
                den += w * g_gd[gi];
                #pragma unroll
                for (int c = 0; c < 12; ++c) cc[c] += w * g_gc[c*1000000 + gi];
            }
        }
        if (dzv) {
            #pragma unroll
            for (int c = 0; c < 12; ++c) smf[FB_PCC_OFF/4 + p*13 + c] = cc[c];
            smf[FB_PCC_OFF/4 + p*13 + 12] = den;
        }
        __syncthreads();
        if (!dzv) {
            #pragma unroll
            for (int c = 0; c < 12; ++c) cc[c] += smf[FB_PCC_OFF/4 + p*13 + c];
            den += smf[FB_PCC_OFF/4 + p*13 + 12];
            const float interval = sqrtf(d0*d0 + d1*d1 + d2*d2);
            const float e = expf(den + ACT_SHIFT_F);
            out_alpha[ray*128 + p] = -expm1f(-interval * log1pf(e));
            bf16x8 f0; bf16x4 f1;
            #pragma unroll
            for (int c = 0; c < 8; ++c) f0[c] = (__bf16)cc[c];
            #pragma unroll
            for (int c = 0; c < 4; ++c) f1[c] = (__bf16)cc[8+c];
            const int swz = (p & 7) << 4;
            *reinterpret_cast<bf16x8*>(smem + ((FB_FEAT_OFF + p*128 +  0) ^ swz)) = f0;
            *reinterpret_cast<bf16x4*>(smem + ((FB_FEAT_OFF + p*128 + 16) ^ swz)) = f1;
        } else {
            float vals[52];
            vals[0] = d0; vals[1] = d1; vals[2] = d2;
            #pragma unroll
            for (int i = 0; i < 3; ++i) {
                const float di = (i == 0) ? d0 : ((i == 1) ? d1 : d2);
                #pragma unroll
                for (int j = 0; j < 4; ++j) {
                    const float a = di * (float)(1 << j);
                    vals[3  + i*4 + j] = sinf(a);
                    vals[15 + i*4 + j] = cosf(a);
                }
            }
            #pragma unroll
            for (int c = 27; c < 52; ++c) vals[c] = 0.0f;
            const int swz = (p & 7) << 4;
            #pragma unroll
            for (int i = 0; i < 13; ++i) {
                bf16x4 v4;
                #pragma unroll
                for (int r = 0; r < 4; ++r) v4[r] = (__bf16)vals[i*4 + r];
                *reinterpret_cast<bf16x4*>(smem + ((FB_FEAT_OFF + p*128 + 24 + i*8) ^ swz)) = v4;
            }
        }
    }
    __syncthreads();
    const int lane = tid & 63;
    const int wid  = tid >> 6;
    const int lr   = lane & 15;
    const int lk   = lane >> 4;
    {
        bf16x8 bf[2][2];
        #pragma unroll
        for (int rt = 0; rt < 2; ++rt)
            #pragma unroll
            for (int ks = 0; ks < 2; ++ks) {
                const int pt = wid*32 + rt*16 + lr;
                int a = FB_FEAT_OFF + pt*128 + ks*64 + lk*16; a ^= (pt & 7) << 4;
                bf[rt][ks] = *reinterpret_cast<const bf16x8*>(smem + a);
            }
        __syncthreads();
        f32x4 acc1[2][8];
        #pragma unroll
        for (int rt = 0; rt < 2; ++rt)
            #pragma unroll
            for (int ct = 0; ct < 8; ++ct) acc1[rt][ct] = (f32x4){0.f,0.f,0.f,0.f};
        #pragma unroll
        for (int ct = 0; ct < 8; ++ct) {
            const bf16x8 aw0 = wf[(ct*2 + 0)*64 + lane];
            const bf16x8 aw1 = wf[(ct*2 + 1)*64 + lane];
            #pragma unroll
            for (int rt = 0; rt < 2; ++rt) {
                acc1[rt][ct] = __builtin_amdgcn_mfma_f32_16x16x32_bf16(aw0, bf[rt][0], acc1[rt][ct], 0, 0, 0);
                acc1[rt][ct] = __builtin_amdgcn_mfma_f32_16x16x32_bf16(aw1, bf[rt][1], acc1[rt][ct], 0, 0, 0);
            }
        }
        #pragma unroll
        for (int ct = 0; ct < 8; ++ct) {
            const f32x4 b1v = *reinterpret_cast<const f32x4*>(g_b1 + ct*16 + lk*4);
            #pragma unroll
            for (int rt = 0; rt < 2; ++rt) {
                const int pt = wid*32 + rt*16 + lr;
                bf16x4 hv;
                #pragma unroll
                for (int r = 0; r < 4; ++r)
                    hv[r] = (__bf16)fmaxf(acc1[rt][ct][r] + b1v[r], 0.0f);
                int a = FB_H1_OFF + pt*256 + ct*32 + lk*8; a ^= (pt & 7) << 4;
                *reinterpret_cast<bf16x4*>(smem + a) = hv;
            }
        }
    }
    __syncthreads();
    const int wr = wid >> 1, wc = wid & 1;
    f32x4 acc2[4][4];
    #pragma unroll
    for (int rt = 0; rt < 4; ++rt)
        #pragma unroll
        for (int ct = 0; ct < 4; ++ct) acc2[rt][ct] = (f32x4){0.f,0.f,0.f,0.f};
    #pragma unroll
    for (int ks = 0; ks < 4; ++ks) {
        bf16x8 a2[4];
        #pragma unroll
        for (int rt = 0; rt < 4; ++rt) {
            const int pt = wr*64 + rt*16 + lr;
            int a = FB_H1_OFF + pt*256 + ks*64 + lk*16; a ^= (pt & 7) << 4;
            a2[rt] = *reinterpret_cast<const bf16x8*>(smem + a);
        }
        #pragma unroll
        for (int ct = 0; ct < 4; ++ct) {
            const int ctg = wc*4 + ct;
            const bf16x8 b2f = wf[1024 + (ctg*4 + ks)*64 + lane];
            #pragma unroll
            for (int rt = 0; rt < 4; ++rt)
                acc2[rt][ct] = __builtin_amdgcn_mfma_f32_16x16x32_bf16(a2[rt], b2f, acc2[rt][ct], 0, 0, 0);
        }
    }
    __syncthreads();
    {
        float b2v[4], w30[4], w31[4], w32[4];
        #pragma unroll
        for (int ct = 0; ct < 4; ++ct) {
            const int n2 = wc*64 + ct*16 + lr;
            b2v[ct] = g_b2[n2];
            w30[ct] = g_w3[n2*3 + 0];
            w31[ct] = g_w3[n2*3 + 1];
            w32[ct] = g_w3[n2*3 + 2];
        }
        #pragma unroll
        for (int rt = 0; rt < 4; ++rt)
            #pragma unroll
            for (int r = 0; r < 4; ++r) {
                float s0 = 0.f, s1 = 0.f, s2 = 0.f;
                #pragma unroll
                for (int ct = 0; ct < 4; ++ct) {
                    const float v = fmaxf(acc2[rt][ct][r] + b2v[ct], 0.0f);
                    s0 = fmaf(v, w30[ct], s0);
                    s1 = fmaf(v, w31[ct], s1);
                    s2 = fmaf(v, w32[ct], s2);
                }
                #pragma unroll
                for (int off = 1; off < 16; off <<= 1) {
                    s0 += __shfl_xor(s0, off);
                    s1 += __shfl_xor(s1, off);
                    s2 += __shfl_xor(s2, off);
                }
                if (lr == 0) {
                    const int pt = wr*64 + rt*16 + lk*4 + r;
                    const int base = FB_PRGB_OFF/4 + (wc*128 + pt)*3;
                    smf[base + 0] = s0;
                    smf[base + 1] = s1;
                    smf[base + 2] = s2;
                }
            }
    }
    __syncthreads();
    if (tid < 128) {
        const int p = tid;
        const float s0 = smf[p*3 + 0] + smf[(128 + p)*3 + 0] + g_b3[0];
        const float s1 = smf[p*3 + 1] + smf[(128 + p)*3 + 1] + g_b3[1];
        const float s2 = smf[p*3 + 2] + smf[(128 + p)*3 + 2] + g_b3[2];
        const int pt = ray*128 + p;
        out_rgb[pt*3 + 0] = 1.0f / (1.0f + expf(-s0));
        out_rgb[pt*3 + 1] = 1.0f / (1.0f + expf(-s1));
        out_rgb[pt*3 + 2] = 1.0f / (1.0f + expf(-s2));
    }
}

extern "C" void kernel_launch(void* const* d_in, const int* in_sizes, int n_in,
                              void* d_out, int out_size, void* d_ws, size_t ws_size,
                              hipStream_t stream)
{
    const float* g_org = (const float*)d_in[0];
    const float* g_dir = (const float*)d_in[1];
    const float* g_len = (const float*)d_in[2];
    const float* g_gd  = (const float*)d_in[3];
    const float* g_gc  = (const float*)d_in[4];
    const float* g_w1  = (const float*)d_in[5];
    const float* g_b1  = (const float*)d_in[6];
    const float* g_w2  = (const float*)d_in[7];
    const float* g_b2  = (const float*)d_in[8];
    const float* g_w3  = (const float*)d_in[9];
    const float* g_b3  = (const float*)d_in[10];
    float* out = (float*)d_out;

    __bf16* wsb  = (__bf16*)d_ws;
    __bf16* emb  = (__bf16*)((char*)d_ws + EMB_B);
    bf16x8* pack = (bf16x8*)((char*)d_ws + PACK_B);

    if (ws_size >= NEED_FULL) {
        __bf16* feat = (__bf16*)((char*)d_ws + FEAT_B);
        dvgo_prep<<<4027, 256, 0, stream>>>(g_gd, g_gc, g_w1, g_w2, g_w3, g_dir,
                                            pack, wsb, emb, 3907);
        dvgo_gather<<<2048, 256, 0, stream>>>(g_org, g_dir, g_len, pack, feat, out);
        dvgo_mlp<<<4096, 256, 0, stream>>>((const bf16x8*)wsb, emb, feat,
                                           g_b1, g_b2, g_b3, out + 4096*128);
    } else if (ws_size >= NEED_PACK) {
        dvgo_prep<<<4011, 256, 0, stream>>>(g_gd, g_gc, g_w1, g_w2, g_w3, g_dir,
                                            pack, wsb, emb, 3907);
        dvgo_main<true><<<4096, 256, 0, stream>>>(g_org, g_dir, g_len, g_gd, g_gc,
                                                  g_b1, g_b2, g_w3, g_b3,
                                                  (const bf16x8*)wsb, pack,
                                                  out, out + 4096*128);
    } else {
        dvgo_prep<<<104, 256, 0, stream>>>(g_gd, g_gc, g_w1, g_w2, g_w3, g_dir,
                                           pack, wsb, emb, 0);
        dvgo_main<false><<<4096, 256, 0, stream>>>(g_org, g_dir, g_len, g_gd, g_gc,
                                                   g_b1, g_b2, g_w3, g_b3,
                                                   (const bf16x8*)wsb, nullptr,
                                                   out, out + 4096*128);
    }
}